// Round 5
// baseline (351.370 us; speedup 1.0000x reference)
//
#include <hip/hip_runtime.h>

#define NN 4096
#define BB 32
#define UU 64
#define MAXNNZ 96

typedef float f32x4 __attribute__((ext_vector_type(4)));
typedef float f32x2 __attribute__((ext_vector_type(2)));
typedef short bf16x8 __attribute__((ext_vector_type(8)));
typedef unsigned short us8 __attribute__((ext_vector_type(8)));
typedef unsigned short us4 __attribute__((ext_vector_type(4)));

__device__ __forceinline__ float bf2f(unsigned short u) {
    return __uint_as_float(((unsigned)u) << 16);
}
__device__ __forceinline__ unsigned short f2bf(float f) {
    unsigned x = __float_as_uint(f);
    x += 0x7fffu + ((x >> 16) & 1u);
    return (unsigned short)(x >> 16);
}

// ---------------------------------------------------------------------------
// K1: dense support (4096x4096 f32) -> padded ELL (cols int32, vals f32, cnt)
// ---------------------------------------------------------------------------
__global__ void build_ell(const float* __restrict__ sup, int* __restrict__ cols,
                          float* __restrict__ vals, int* __restrict__ cnt) {
    int row  = blockIdx.x * 4 + (threadIdx.x >> 6);
    int lane = threadIdx.x & 63;
    const float* rp = sup + (size_t)row * NN;
    int base = 0;
    for (int ch = 0; ch < NN / 64; ++ch) {
        float v = rp[ch * 64 + lane];
        unsigned long long m = __ballot(v != 0.0f);
        int pos = __popcll(m & ((1ull << lane) - 1ull));
        if (v != 0.0f) {
            int idx = base + pos;
            if (idx < MAXNNZ) {
                cols[row * MAXNNZ + idx] = ch * 64 + lane;
                vals[row * MAXNNZ + idx] = v;
            }
        }
        base += __popcll(m);
    }
    if (lane == 0) cnt[row] = base < MAXNNZ ? base : MAXNNZ;
}

// ---------------------------------------------------------------------------
// K2: build Xall (N x 4096) bf16: cols [0,2048) = inputs, [2048,4096) = hx
// ---------------------------------------------------------------------------
__global__ void build_x0(const float* __restrict__ inp, const float* __restrict__ hxp,
                         unsigned short* __restrict__ Xall) {
    size_t tt = (size_t)blockIdx.x * 256 + threadIdx.x;
    size_t e  = tt * 4;
    int half  = e >= (size_t)8388608;
    size_t id = e & 8388607ull;               // b*262144 + n*64 + d
    const float* src = half ? hxp : inp;
    float4 f = *(const float4*)(src + id);
    int d = (int)(id & 63);
    int n = (int)((id >> 6) & 4095);
    int b = (int)(id >> 18);
    us4 o;
    o[0] = f2bf(f.x); o[1] = f2bf(f.y); o[2] = f2bf(f.z); o[3] = f2bf(f.w);
    *(us4*)(Xall + (size_t)n * 4096 + (size_t)half * 2048 + b * 64 + d) = o;
}

// ---------------------------------------------------------------------------
// K3: permute + transpose + bf16-cast weights.
// f = m*128 + s  (m in 0..2, s in 0..127), original row s*3+m.
// ---------------------------------------------------------------------------
__global__ void prep_w(const float* __restrict__ Wru, const float* __restrict__ Wc,
                       unsigned short* __restrict__ Wt1, unsigned short* __restrict__ Wt2) {
    int t = blockIdx.x * 256 + threadIdx.x;   // grid 288*256 = 73728 exactly
    if (t < 49152) {
        int o = t / 384, f = t - o * 384;
        int s = f & 127, m = f >> 7;
        Wt1[t] = f2bf(Wru[(s * 3 + m) * 128 + o]);
    } else {
        int u = t - 49152;
        int o = u / 384, f = u - o * 384;
        int s = f & 127, m = f >> 7;
        Wt2[u] = f2bf(Wc[(s * 3 + m) * 64 + o]);
    }
}

// ---------------------------------------------------------------------------
// SpMM: Y[row, c] = sum_k vals[row,k] * X[cols[row,k], c]
// CHEB: Y = 2*(L@X) - Z0
// One wave per (row, 512-col chunk); 8 cols/lane (16B gathers), 8 in flight.
// ---------------------------------------------------------------------------
template <bool CHEB>
__launch_bounds__(256)
__global__ void spmm_kernel(const int* __restrict__ cols, const float* __restrict__ vals,
                            const int* __restrict__ cnt, const unsigned short* __restrict__ X,
                            const unsigned short* __restrict__ Z0,
                            unsigned short* __restrict__ Y, int ncols) {
    int T = gridDim.x;
    int fid = blockIdx.x;
    int v = (fid & 7) * (T >> 3) + (fid >> 3);   // XCD k owns v in [k*T/8,(k+1)*T/8)
    int chunk = v >> 10;                          // 1024 row-groups per chunk
    int rg = v & 1023;
    int row = __builtin_amdgcn_readfirstlane(rg * 4 + (threadIdx.x >> 6));
    int lane = threadIdx.x & 63;
    int c = chunk * 512 + lane * 8;
    const int* cp = cols + row * MAXNNZ;
    const float* vp = vals + row * MAXNNZ;
    int kc = cnt[row];
    f32x2 acc0 = {0.f, 0.f}, acc1 = {0.f, 0.f}, acc2 = {0.f, 0.f}, acc3 = {0.f, 0.f};
    int k = 0;
    for (; k + 8 <= kc; k += 8) {
        us8 xx[8];
        float ss[8];
#pragma unroll
        for (int u = 0; u < 8; ++u) {
            xx[u] = *(const us8*)(X + (size_t)cp[k + u] * ncols + c);
            ss[u] = vp[k + u];
        }
#pragma unroll
        for (int u = 0; u < 8; ++u) {
            f32x2 w = {ss[u], ss[u]};
            const unsigned* p = (const unsigned*)&xx[u];
            f32x2 xv;
            xv.x = __uint_as_float(p[0] << 16); xv.y = __uint_as_float(p[0] & 0xffff0000u);
            acc0 = __builtin_elementwise_fma(w, xv, acc0);
            xv.x = __uint_as_float(p[1] << 16); xv.y = __uint_as_float(p[1] & 0xffff0000u);
            acc1 = __builtin_elementwise_fma(w, xv, acc1);
            xv.x = __uint_as_float(p[2] << 16); xv.y = __uint_as_float(p[2] & 0xffff0000u);
            acc2 = __builtin_elementwise_fma(w, xv, acc2);
            xv.x = __uint_as_float(p[3] << 16); xv.y = __uint_as_float(p[3] & 0xffff0000u);
            acc3 = __builtin_elementwise_fma(w, xv, acc3);
        }
    }
    for (; k < kc; ++k) {
        int j = cp[k];
        float s = vp[k];
        f32x2 w = {s, s};
        us8 x = *(const us8*)(X + (size_t)j * ncols + c);
        const unsigned* p = (const unsigned*)&x;
        f32x2 xv;
        xv.x = __uint_as_float(p[0] << 16); xv.y = __uint_as_float(p[0] & 0xffff0000u);
        acc0 = __builtin_elementwise_fma(w, xv, acc0);
        xv.x = __uint_as_float(p[1] << 16); xv.y = __uint_as_float(p[1] & 0xffff0000u);
        acc1 = __builtin_elementwise_fma(w, xv, acc1);
        xv.x = __uint_as_float(p[2] << 16); xv.y = __uint_as_float(p[2] & 0xffff0000u);
        acc2 = __builtin_elementwise_fma(w, xv, acc2);
        xv.x = __uint_as_float(p[3] << 16); xv.y = __uint_as_float(p[3] & 0xffff0000u);
        acc3 = __builtin_elementwise_fma(w, xv, acc3);
    }
    float a[8] = {acc0.x, acc0.y, acc1.x, acc1.y, acc2.x, acc2.y, acc3.x, acc3.y};
    if (CHEB) {
        us8 z = __builtin_nontemporal_load((const us8*)(Z0 + (size_t)row * ncols + c));
        const unsigned* pz = (const unsigned*)&z;
#pragma unroll
        for (int i = 0; i < 4; ++i) {
            a[2 * i]     = 2.f * a[2 * i]     - __uint_as_float(pz[i] << 16);
            a[2 * i + 1] = 2.f * a[2 * i + 1] - __uint_as_float(pz[i] & 0xffff0000u);
        }
    }
    us8 o;
#pragma unroll
    for (int i = 0; i < 8; ++i) o[i] = f2bf(a[i]);
    __builtin_nontemporal_store(o, (us8*)(Y + (size_t)row * ncols + c));
}

// ---------------------------------------------------------------------------
// Feature GEMM, LDS-free, col-split: one wave = (node, col-half).
// 32 GEMM rows (b=0..31) x NCT*16 output cols. MFMA operands loaded directly
// from global in fragment layout. acc footprint halved vs round 4 (32/16
// VGPR) so each k-step's loads batch in registers -> MLP; grid doubled to
// 2048 blocks -> 8192 waves.
// GATE: col-half 0 = r-gate (cols 0..63) -> r*h; half 1 = u-gate -> ubuf.
// FINAL: tanh -> out = u*h + (1-u)*c.
// ---------------------------------------------------------------------------
template <bool GATE>
__launch_bounds__(256, 3)
__global__ void gemm_kernel(
    const unsigned short* __restrict__ s0, const unsigned short* __restrict__ s1,
    const unsigned short* __restrict__ s2, const unsigned short* __restrict__ s3,
    const unsigned short* __restrict__ s4, const unsigned short* __restrict__ s5,
    int strideSt,
    const unsigned short* __restrict__ Wt, const float* __restrict__ bias,
    const float* __restrict__ hx, unsigned short* __restrict__ ubuf,
    unsigned short* __restrict__ x2st, float* __restrict__ outp) {
    constexpr int NCT = GATE ? 4 : 2;        // col tiles of 16 per wave
    const int t = threadIdx.x;
    const int w = t >> 6, l = t & 63;
    const int bidx = blockIdx.x;
    const int n = (bidx >> 1) * 4 + w;       // node (pairs share A -> L2 hits)
    const int chh = bidx & 1;                // col half
    const int colBase = chh * (NCT * 16);
    const int lr = l & 15;                   // fragment row (A) / col (B)
    const int kg = l >> 4;                   // k subgroup (8 elems)
    const unsigned short* srcs[6] = {s0, s1, s2, s3, s4, s5};

    f32x4 acc[2][NCT];
#pragma unroll
    for (int g = 0; g < 2; ++g)
#pragma unroll
        for (int ct = 0; ct < NCT; ++ct)
#pragma unroll
            for (int r2 = 0; r2 < 4; ++r2) acc[g][ct][r2] = 0.f;

    // per-lane W base: row (=output col) colBase+lr, k offset kg*8
    const unsigned short* wl = Wt + (colBase + lr) * 384 + kg * 8;

#pragma unroll
    for (int kk = 0; kk < 12; ++kk) {
        const int si = kk >> 1;
        const unsigned short* src = srcs[si];
        const int stride = (si & 1) ? strideSt : NN;
        const int dwin = (kk & 1) * 32;
        bf16x8 aF[2];
#pragma unroll
        for (int g = 0; g < 2; ++g) {
            const unsigned short* ap =
                src + (size_t)n * stride + (g * 16 + lr) * 64 + dwin + kg * 8;
            aF[g] = *(const bf16x8*)ap;
        }
        bf16x8 wF[NCT];
#pragma unroll
        for (int ct = 0; ct < NCT; ++ct)
            wF[ct] = *(const bf16x8*)(wl + ct * (16 * 384) + kk * 32);
#pragma unroll
        for (int ct = 0; ct < NCT; ++ct) {
#pragma unroll
            for (int g = 0; g < 2; ++g)
                acc[g][ct] =
                    __builtin_amdgcn_mfma_f32_16x16x32_bf16(aF[g], wF[ct], acc[g][ct], 0, 0, 0);
        }
    }

    // epilogue: C/D fragment: col = colBase + ct*16 + lr, row b = g*16 + kg*4 + rr
    if (GATE) {
        if (chh == 0) {  // r-gate cols 0..63 (block-uniform branch)
#pragma unroll
            for (int ct = 0; ct < NCT; ++ct) {
                const int col = ct * 16 + lr;
                const float bs = bias[col];
#pragma unroll
                for (int g = 0; g < 2; ++g) {
#pragma unroll
                    for (int rr = 0; rr < 4; ++rr) {
                        const int b = g * 16 + kg * 4 + rr;
                        float vv = acc[g][ct][rr] + bs;
                        float s = 1.f / (1.f + __expf(-vv));
                        float h = hx[(size_t)b * (NN * UU) + (size_t)n * UU + col];
                        x2st[(size_t)n * 2048 + b * 64 + col] = f2bf(s * h);
                    }
                }
            }
        } else {         // u-gate cols 64..127
#pragma unroll
            for (int ct = 0; ct < NCT; ++ct) {
                const int col = 64 + ct * 16 + lr;
                const float bs = bias[col];
#pragma unroll
                for (int g = 0; g < 2; ++g) {
#pragma unroll
                    for (int rr = 0; rr < 4; ++rr) {
                        const int b = g * 16 + kg * 4 + rr;
                        float vv = acc[g][ct][rr] + bs;
                        float s = 1.f / (1.f + __expf(-vv));
                        ubuf[(size_t)n * 2048 + b * 64 + (col - 64)] = f2bf(s);
                    }
                }
            }
        }
    } else {
#pragma unroll
        for (int ct = 0; ct < NCT; ++ct) {
            const int col = colBase + ct * 16 + lr;
            const float bs = bias[col];
#pragma unroll
            for (int g = 0; g < 2; ++g) {
#pragma unroll
                for (int rr = 0; rr < 4; ++rr) {
                    const int b = g * 16 + kg * 4 + rr;
                    float vv = acc[g][ct][rr] + bs;
                    // tanh(x) = 1 - 2/(exp(2x)+1)
                    float e = __expf(2.f * vv);
                    float cc = 1.f - 2.f / (e + 1.f);
                    size_t idx = (size_t)b * (NN * UU) + (size_t)n * UU + col;
                    float u = bf2f(ubuf[(size_t)n * 2048 + b * 64 + col]);
                    float h = hx[idx];
                    outp[idx] = u * h + (1.f - u) * cc;
                }
            }
        }
    }
}

// ---------------------------------------------------------------------------
extern "C" void kernel_launch(void* const* d_in, const int* in_sizes, int n_in,
                              void* d_out, int out_size, void* d_ws, size_t ws_size,
                              hipStream_t stream) {
    const float* inputs  = (const float*)d_in[0];
    const float* hx      = (const float*)d_in[1];
    const float* support = (const float*)d_in[2];
    const float* W_ru    = (const float*)d_in[3];
    const float* b_ru    = (const float*)d_in[4];
    const float* W_c     = (const float*)d_in[5];
    const float* b_c     = (const float*)d_in[6];
    float* out = (float*)d_out;

    char* ws = (char*)d_ws;
    size_t off = 0;
    auto alloc = [&](size_t bytes) -> char* {
        char* p = ws + off;
        off = (off + bytes + 255) & ~(size_t)255;
        return p;
    };
    int*            colsI = (int*)  alloc((size_t)NN * MAXNNZ * 4);
    float*          valsF = (float*)alloc((size_t)NN * MAXNNZ * 4);
    int*            cntI  = (int*)  alloc((size_t)NN * 4);
    unsigned short* Wt1   = (unsigned short*)alloc(128 * 384 * 2);
    unsigned short* Wt2   = (unsigned short*)alloc(64 * 384 * 2);
    unsigned short* Xall  = (unsigned short*)alloc((size_t)NN * 4096 * 2);
    unsigned short* Z1    = (unsigned short*)alloc((size_t)NN * 4096 * 2);
    unsigned short* Z2    = (unsigned short*)alloc((size_t)NN * 4096 * 2);
    unsigned short* X2st  = (unsigned short*)alloc((size_t)NN * 2048 * 2);
    unsigned short* Z1st  = (unsigned short*)alloc((size_t)NN * 2048 * 2);
    unsigned short* Z2st  = (unsigned short*)alloc((size_t)NN * 2048 * 2);
    unsigned short* ubuf  = (unsigned short*)alloc((size_t)NN * 2048 * 2);
    if (off > ws_size) return;  // workspace too small -> loud validation failure

    build_ell<<<1024, 256, 0, stream>>>(support, colsI, valsF, cntI);
    build_x0<<<16384, 256, 0, stream>>>(inputs, hx, Xall);
    prep_w<<<288, 256, 0, stream>>>(W_ru, W_c, Wt1, Wt2);

    // gconv1 diffusion over all 4096 columns (8 chunks of 512)
    spmm_kernel<false><<<8192, 256, 0, stream>>>(colsI, valsF, cntI, Xall, Xall, Z1, 4096);
    spmm_kernel<true><<<8192, 256, 0, stream>>>(colsI, valsF, cntI, Z1, Xall, Z2, 4096);
    // gate GEMM -> r*h (X2st) and u (ubuf)
    gemm_kernel<true><<<2048, 256, 0, stream>>>(Xall, Xall + 2048, Z1, Z1 + 2048,
                                                Z2, Z2 + 2048, 4096, Wt1, b_ru, hx,
                                                ubuf, X2st, nullptr);
    // gconv2 diffusion: only the 2048 state columns (4 chunks of 512)
    spmm_kernel<false><<<4096, 256, 0, stream>>>(colsI, valsF, cntI, X2st, X2st, Z1st, 2048);
    spmm_kernel<true><<<4096, 256, 0, stream>>>(colsI, valsF, cntI, Z1st, X2st, Z2st, 2048);
    // candidate GEMM + GRU combine -> out
    gemm_kernel<false><<<2048, 256, 0, stream>>>(Xall, X2st, Z1, Z1st, Z2, Z2st, 2048,
                                                 Wt2, b_c, hx, ubuf, nullptr, out);
}

// Round 6
// 286.415 us; speedup vs baseline: 1.2268x; 1.2268x over previous
//
#include <hip/hip_runtime.h>

#define NN 4096
#define BB 32
#define UU 64
#define MAXNNZ 96

typedef float f32x4 __attribute__((ext_vector_type(4)));
typedef float f32x2 __attribute__((ext_vector_type(2)));
typedef short bf16x8 __attribute__((ext_vector_type(8)));
typedef unsigned short us8 __attribute__((ext_vector_type(8)));
typedef unsigned short us4 __attribute__((ext_vector_type(4)));

__device__ __forceinline__ float bf2f(unsigned short u) {
    return __uint_as_float(((unsigned)u) << 16);
}
__device__ __forceinline__ unsigned short f2bf(float f) {
    unsigned x = __float_as_uint(f);
    x += 0x7fffu + ((x >> 16) & 1u);
    return (unsigned short)(x >> 16);
}

// Packed column order within each 2048-wide src (b in 0..31, d in 0..63):
//   off(b,d) = (d>>5)*1024 + (b>>4)*512 + ((d>>3)&3)*128 + (b&15)*8 + (d&7)
// i.e. [dwin][g][kg][lr][e] -- exactly the MFMA B-fragment load order:
// lane l reads 8 contiguous elems at dwin*1024 + g*512 + l*8.

// ---------------------------------------------------------------------------
// K1: dense support (4096x4096 f32) -> padded ELL (cols int32, vals f32, cnt)
// ---------------------------------------------------------------------------
__global__ void build_ell(const float* __restrict__ sup, int* __restrict__ cols,
                          float* __restrict__ vals, int* __restrict__ cnt) {
    int row  = blockIdx.x * 4 + (threadIdx.x >> 6);
    int lane = threadIdx.x & 63;
    const float* rp = sup + (size_t)row * NN;
    int base = 0;
    for (int ch = 0; ch < NN / 64; ++ch) {
        float v = rp[ch * 64 + lane];
        unsigned long long m = __ballot(v != 0.0f);
        int pos = __popcll(m & ((1ull << lane) - 1ull));
        if (v != 0.0f) {
            int idx = base + pos;
            if (idx < MAXNNZ) {
                cols[row * MAXNNZ + idx] = ch * 64 + lane;
                vals[row * MAXNNZ + idx] = v;
            }
        }
        base += __popcll(m);
    }
    if (lane == 0) cnt[row] = base < MAXNNZ ? base : MAXNNZ;
}

// ---------------------------------------------------------------------------
// K2: build Xall (N x 4096) bf16 in packed column order.
//   cols [0,2048) = inputs, [2048,4096) = hx
// ---------------------------------------------------------------------------
__global__ void build_x0(const float* __restrict__ inp, const float* __restrict__ hxp,
                         unsigned short* __restrict__ Xall) {
    size_t tt = (size_t)blockIdx.x * 256 + threadIdx.x;
    size_t e  = tt * 4;
    int half  = e >= (size_t)8388608;
    size_t id = e & 8388607ull;               // b*262144 + n*64 + d
    const float* src = half ? hxp : inp;
    float4 f = *(const float4*)(src + id);
    int d = (int)(id & 63);                   // multiple of 4
    int n = (int)((id >> 6) & 4095);
    int b = (int)(id >> 18);
    int off = half * 2048 + (d >> 5) * 1024 + (b >> 4) * 512 + ((d >> 3) & 3) * 128 +
              (b & 15) * 8 + (d & 7);
    us4 o;
    o[0] = f2bf(f.x); o[1] = f2bf(f.y); o[2] = f2bf(f.z); o[3] = f2bf(f.w);
    *(us4*)(Xall + (size_t)n * 4096 + off) = o;
}

// ---------------------------------------------------------------------------
// K3: pack weights in per-lane fragment order for the A-operand (W as MFMA
// first arg): Wp[ct][kk][lane][e] = W[u = ct*16 + (lane&15)]
//                                    [k = kk*32 + (lane>>4)*8 + e]
// with original W row = (s*3+m)*... where k = m*128 + s.
// Gate: 8 ct tiles (49152 elems). Final: 4 ct tiles (24576 elems).
// ---------------------------------------------------------------------------
__global__ void prep_w(const float* __restrict__ Wru, const float* __restrict__ Wc,
                       unsigned short* __restrict__ Wp1, unsigned short* __restrict__ Wp2) {
    int t = blockIdx.x * 256 + threadIdx.x;   // grid 288*256 = 73728 exactly
    int e  = t & 7;
    int li = (t >> 3) & 63;
    int lr = li & 15, kg = li >> 4;
    if (t < 49152) {
        int q = t >> 9;                        // ct*12 + kk, 0..95
        int ct = q / 12, kk = q - ct * 12;
        int u = ct * 16 + lr;
        int k = kk * 32 + kg * 8 + e;
        int s = k & 127, m = k >> 7;
        Wp1[t] = f2bf(Wru[(s * 3 + m) * 128 + u]);
    } else {
        int tt = t - 49152;                    // < 24576
        int q = tt >> 9;                       // 0..47
        int ct = q / 12, kk = q - ct * 12;
        int u = ct * 16 + lr;
        int k = kk * 32 + kg * 8 + e;
        int s = k & 127, m = k >> 7;
        Wp2[tt] = f2bf(Wc[(s * 3 + m) * 64 + u]);
    }
}

// ---------------------------------------------------------------------------
// SpMM: Y[row, c] = sum_k vals[row,k] * X[cols[row,k], c]   (column-agnostic)
// CHEB: Y = 2*(L@X) - Z0
// One wave per (row, 512-col chunk); 8 cols/lane (16B gathers), 8 in flight.
// ---------------------------------------------------------------------------
template <bool CHEB>
__launch_bounds__(256)
__global__ void spmm_kernel(const int* __restrict__ cols, const float* __restrict__ vals,
                            const int* __restrict__ cnt, const unsigned short* __restrict__ X,
                            const unsigned short* __restrict__ Z0,
                            unsigned short* __restrict__ Y, int ncols) {
    int T = gridDim.x;
    int fid = blockIdx.x;
    int v = (fid & 7) * (T >> 3) + (fid >> 3);   // XCD k owns v in [k*T/8,(k+1)*T/8)
    int chunk = v >> 10;                          // 1024 row-groups per chunk
    int rg = v & 1023;
    int row = __builtin_amdgcn_readfirstlane(rg * 4 + (threadIdx.x >> 6));
    int lane = threadIdx.x & 63;
    int c = chunk * 512 + lane * 8;
    const int* cp = cols + row * MAXNNZ;
    const float* vp = vals + row * MAXNNZ;
    int kc = cnt[row];
    f32x2 acc0 = {0.f, 0.f}, acc1 = {0.f, 0.f}, acc2 = {0.f, 0.f}, acc3 = {0.f, 0.f};
    int k = 0;
    for (; k + 8 <= kc; k += 8) {
        us8 xx[8];
        float ss[8];
#pragma unroll
        for (int u = 0; u < 8; ++u) {
            xx[u] = *(const us8*)(X + (size_t)cp[k + u] * ncols + c);
            ss[u] = vp[k + u];
        }
#pragma unroll
        for (int u = 0; u < 8; ++u) {
            f32x2 w = {ss[u], ss[u]};
            const unsigned* p = (const unsigned*)&xx[u];
            f32x2 xv;
            xv.x = __uint_as_float(p[0] << 16); xv.y = __uint_as_float(p[0] & 0xffff0000u);
            acc0 = __builtin_elementwise_fma(w, xv, acc0);
            xv.x = __uint_as_float(p[1] << 16); xv.y = __uint_as_float(p[1] & 0xffff0000u);
            acc1 = __builtin_elementwise_fma(w, xv, acc1);
            xv.x = __uint_as_float(p[2] << 16); xv.y = __uint_as_float(p[2] & 0xffff0000u);
            acc2 = __builtin_elementwise_fma(w, xv, acc2);
            xv.x = __uint_as_float(p[3] << 16); xv.y = __uint_as_float(p[3] & 0xffff0000u);
            acc3 = __builtin_elementwise_fma(w, xv, acc3);
        }
    }
    for (; k < kc; ++k) {
        int j = cp[k];
        float s = vp[k];
        f32x2 w = {s, s};
        us8 x = *(const us8*)(X + (size_t)j * ncols + c);
        const unsigned* p = (const unsigned*)&x;
        f32x2 xv;
        xv.x = __uint_as_float(p[0] << 16); xv.y = __uint_as_float(p[0] & 0xffff0000u);
        acc0 = __builtin_elementwise_fma(w, xv, acc0);
        xv.x = __uint_as_float(p[1] << 16); xv.y = __uint_as_float(p[1] & 0xffff0000u);
        acc1 = __builtin_elementwise_fma(w, xv, acc1);
        xv.x = __uint_as_float(p[2] << 16); xv.y = __uint_as_float(p[2] & 0xffff0000u);
        acc2 = __builtin_elementwise_fma(w, xv, acc2);
        xv.x = __uint_as_float(p[3] << 16); xv.y = __uint_as_float(p[3] & 0xffff0000u);
        acc3 = __builtin_elementwise_fma(w, xv, acc3);
    }
    float a[8] = {acc0.x, acc0.y, acc1.x, acc1.y, acc2.x, acc2.y, acc3.x, acc3.y};
    if (CHEB) {
        us8 z = __builtin_nontemporal_load((const us8*)(Z0 + (size_t)row * ncols + c));
        const unsigned* pz = (const unsigned*)&z;
#pragma unroll
        for (int i = 0; i < 4; ++i) {
            a[2 * i]     = 2.f * a[2 * i]     - __uint_as_float(pz[i] << 16);
            a[2 * i + 1] = 2.f * a[2 * i + 1] - __uint_as_float(pz[i] & 0xffff0000u);
        }
    }
    us8 o;
#pragma unroll
    for (int i = 0; i < 8; ++i) o[i] = f2bf(a[i]);
    __builtin_nontemporal_store(o, (us8*)(Y + (size_t)row * ncols + c));
}

// ---------------------------------------------------------------------------
// Feature GEMM v6: W staged ONCE to LDS (48KB, fragment-packed, conflict-free
// lane-linear ds_read_b128); A read directly from global in packed fragment
// order (contiguous 1KB per instruction). No barriers in the k-loop. MFMA
// operands swapped (W first) so D rows = output col, D cols = batch ->
// contiguous us4/float4 epilogue accesses.
// Block = 512 thr = 8 waves = 8 nodes. MODE 0 = gate (grid 1024: 512 node
// groups x 2 col halves, paired on same XCD); MODE 1 = final (grid 512).
// ---------------------------------------------------------------------------
template <int MODE>
__launch_bounds__(512, 6)
__global__ void gemm_kernel(
    const unsigned short* __restrict__ baseIn, size_t bufIn, int rowIn,
    const unsigned short* __restrict__ baseSt, size_t bufSt, int rowSt,
    const unsigned short* __restrict__ Wp, const float* __restrict__ bias,
    const float* __restrict__ hx, unsigned short* __restrict__ ubuf,
    unsigned short* __restrict__ x2st, float* __restrict__ outp) {
    __shared__ __align__(16) unsigned short Wl[24576];  // 48 KB
    const int t = threadIdx.x;
    const int w = t >> 6, l = t & 63;
    const int bid = blockIdx.x;
    int h, ng;
    if (MODE == 0) { h = (bid >> 3) & 1; ng = (bid & 7) | ((bid >> 4) << 3); }
    else           { h = 0;             ng = bid; }
    const unsigned short* wsrc = Wp + (MODE == 0 ? h * 24576 : 0);
#pragma unroll
    for (int i = 0; i < 6; ++i) {
        int idx = i * 512 + t;
        *(us8*)(&Wl[idx * 8]) = *(const us8*)(wsrc + idx * 8);
    }
    __syncthreads();

    const int n = ng * 8 + w;
    f32x4 acc[4][2];
#pragma unroll
    for (int ct = 0; ct < 4; ++ct)
#pragma unroll
        for (int g = 0; g < 2; ++g)
#pragma unroll
            for (int r2 = 0; r2 < 4; ++r2) acc[ct][g][r2] = 0.f;

    for (int si = 0; si < 6; ++si) {
        const unsigned short* s = (si & 1)
            ? baseSt + (size_t)(si >> 1) * bufSt + (size_t)n * rowSt
            : baseIn + (size_t)(si >> 1) * bufIn + (size_t)n * rowIn;
        us8 aB[4];
#pragma unroll
        for (int dg = 0; dg < 4; ++dg)        // dg = dwin*2 + g
            aB[dg] = *(const us8*)(s + dg * 512 + l * 8);
#pragma unroll
        for (int dwin = 0; dwin < 2; ++dwin) {
            const int kk = si * 2 + dwin;
            bf16x8 wf[4];
#pragma unroll
            for (int ct = 0; ct < 4; ++ct)
                wf[ct] = *(const bf16x8*)(&Wl[ct * 6144 + kk * 512 + l * 8]);
#pragma unroll
            for (int ct = 0; ct < 4; ++ct)
#pragma unroll
                for (int g = 0; g < 2; ++g)
                    acc[ct][g] = __builtin_amdgcn_mfma_f32_16x16x32_bf16(
                        wf[ct], (bf16x8)aB[dwin * 2 + g], acc[ct][g], 0, 0, 0);
        }
    }

    // epilogue: D row = u = ct*16 + kg*4 + rr, D col = b = g*16 + lr
    const int kg = l >> 4, lr = l & 15;
#pragma unroll
    for (int ct = 0; ct < 4; ++ct) {
        const int u0 = ct * 16 + kg * 4;
        const int pofs = (ct >> 1) * 1024 + ((ct & 1) * 2 + (kg >> 1)) * 128 +
                         lr * 8 + (kg & 1) * 4;
#pragma unroll
        for (int g = 0; g < 2; ++g) {
            const int b = g * 16 + lr;
            if (MODE == 0) {
                if (h == 0) {  // r-gate -> r*h, packed
                    float4 hv = *(const float4*)(hx + (size_t)b * (NN * UU) +
                                                 (size_t)n * UU + u0);
                    us4 o;
#pragma unroll
                    for (int rr = 0; rr < 4; ++rr) {
                        float vv = acc[ct][g][rr] + bias[u0 + rr];
                        float sg = 1.f / (1.f + __expf(-vv));
                        o[rr] = f2bf(sg * ((const float*)&hv)[rr]);
                    }
                    *(us4*)(x2st + (size_t)n * 2048 + g * 512 + pofs) = o;
                } else {       // u-gate -> ubuf, packed
                    us4 o;
#pragma unroll
                    for (int rr = 0; rr < 4; ++rr) {
                        float vv = acc[ct][g][rr] + bias[64 + u0 + rr];
                        float sg = 1.f / (1.f + __expf(-vv));
                        o[rr] = f2bf(sg);
                    }
                    *(us4*)(ubuf + (size_t)n * 2048 + g * 512 + pofs) = o;
                }
            } else {
                float4 hv = *(const float4*)(hx + (size_t)b * (NN * UU) +
                                             (size_t)n * UU + u0);
                us4 uv = *(const us4*)(ubuf + (size_t)n * 2048 + g * 512 + pofs);
                float4 o;
#pragma unroll
                for (int rr = 0; rr < 4; ++rr) {
                    float vv = acc[ct][g][rr] + bias[u0 + rr];
                    float e2 = __expf(2.f * vv);
                    float cc = 1.f - 2.f / (e2 + 1.f);
                    float uu = bf2f(uv[rr]);
                    ((float*)&o)[rr] = uu * ((const float*)&hv)[rr] + (1.f - uu) * cc;
                }
                *(float4*)(outp + (size_t)b * (NN * UU) + (size_t)n * UU + u0) = o;
            }
        }
    }
}

// ---------------------------------------------------------------------------
extern "C" void kernel_launch(void* const* d_in, const int* in_sizes, int n_in,
                              void* d_out, int out_size, void* d_ws, size_t ws_size,
                              hipStream_t stream) {
    const float* inputs  = (const float*)d_in[0];
    const float* hx      = (const float*)d_in[1];
    const float* support = (const float*)d_in[2];
    const float* W_ru    = (const float*)d_in[3];
    const float* b_ru    = (const float*)d_in[4];
    const float* W_c     = (const float*)d_in[5];
    const float* b_c     = (const float*)d_in[6];
    float* out = (float*)d_out;

    char* ws = (char*)d_ws;
    size_t off = 0;
    auto alloc = [&](size_t bytes) -> char* {
        char* p = ws + off;
        off = (off + bytes + 255) & ~(size_t)255;
        return p;
    };
    const size_t BIG = (size_t)NN * 4096;   // elems per wide buffer
    const size_t SML = (size_t)NN * 2048;
    int*            colsI = (int*)  alloc((size_t)NN * MAXNNZ * 4);
    float*          valsF = (float*)alloc((size_t)NN * MAXNNZ * 4);
    int*            cntI  = (int*)  alloc((size_t)NN * 4);
    unsigned short* Wp1   = (unsigned short*)alloc(49152 * 2);
    unsigned short* Wp2   = (unsigned short*)alloc(24576 * 2);
    unsigned short* bufA  = (unsigned short*)alloc(3 * BIG * 2);  // Xall,Z1,Z2
    unsigned short* bufB  = (unsigned short*)alloc(3 * SML * 2);  // X2st,Z1st,Z2st
    unsigned short* ubuf  = (unsigned short*)alloc(SML * 2);
    if (off > ws_size) return;  // workspace too small -> loud validation failure

    unsigned short* Xall = bufA;
    unsigned short* Z1   = bufA + BIG;
    unsigned short* Z2   = bufA + 2 * BIG;
    unsigned short* X2st = bufB;
    unsigned short* Z1st = bufB + SML;
    unsigned short* Z2st = bufB + 2 * SML;

    build_ell<<<1024, 256, 0, stream>>>(support, colsI, valsF, cntI);
    build_x0<<<16384, 256, 0, stream>>>(inputs, hx, Xall);
    prep_w<<<288, 256, 0, stream>>>(W_ru, W_c, Wp1, Wp2);

    // gconv1 diffusion over all 4096 columns (8 chunks of 512)
    spmm_kernel<false><<<8192, 256, 0, stream>>>(colsI, valsF, cntI, Xall, Xall, Z1, 4096);
    spmm_kernel<true><<<8192, 256, 0, stream>>>(colsI, valsF, cntI, Z1, Xall, Z2, 4096);
    // gate GEMM -> r*h (X2st, packed) and u (ubuf, packed)
    gemm_kernel<0><<<1024, 512, 0, stream>>>(Xall, BIG, 4096, Xall + 2048, BIG, 4096,
                                             Wp1, b_ru, hx, ubuf, X2st, nullptr);
    // gconv2 diffusion: only the 2048 state columns (4 chunks of 512)
    spmm_kernel<false><<<4096, 256, 0, stream>>>(colsI, valsF, cntI, X2st, X2st, Z1st, 2048);
    spmm_kernel<true><<<4096, 256, 0, stream>>>(colsI, valsF, cntI, Z1st, X2st, Z2st, 2048);
    // candidate GEMM + GRU combine -> out
    gemm_kernel<1><<<512, 512, 0, stream>>>(Xall, BIG, 4096, X2st, SML, 2048,
                                            Wp2, b_c, hx, ubuf, nullptr, out);
}